// Round 6
// baseline (524.047 us; speedup 1.0000x reference)
//
#include <hip/hip_runtime.h>
#include <hip/hip_bf16.h>
#include <math.h>

#define N 8192
#define NEGV -1000000000.0f
#define EPSV 1e-05f
#define NSPLIT 8
#define CPS (N / NSPLIT)   // 1024 columns per split
#define NTILE (CPS / 64)   // 16 tiles (even -> manual 2x unroll exact)

typedef short bf16x8 __attribute__((ext_vector_type(8)));
typedef float f32x4 __attribute__((ext_vector_type(4)));
typedef unsigned short u16;

// ---- float workspace layout ----
#define WS_SCAL 0
#define WS_H    64                        // N*64 fp32
#define WS_ST   (WS_H + N * 64)           // N
#define WS_SBI  (WS_ST + N)               // N
#define WS_DEN  (WS_SBI + N)              // NSPLIT*N
#define WS_AGG  (WS_DEN + NSPLIT * N)     // NSPLIT*N*64
#define WS_F_END (WS_AGG + NSPLIT * N * 64)
// ---- u16 (bf16) region, offsets in u16 units from (u16*)ws ----
#define WU_BASE (WS_F_END * 2)
#define WU_QB (WU_BASE)                   // N*64
#define WU_KB (WU_BASE + N * 64)          // N*64
#define WU_MB (WU_BASE + 2 * N * 64)      // N*64 (row-major, transposed later)
#define WU_MT (WU_BASE + 3 * N * 64)      // 64*N

static __device__ __forceinline__ u16 f2bf(float f) {
    __hip_bfloat16 h = __float2bfloat16(f);
    return *(u16*)&h;
}

// ---------------- Kernel A: scalar prep ----------------
__global__ void prep_k(const float* __restrict__ tc, const float* __restrict__ wg,
                       const float* __restrict__ bg, const float* __restrict__ sbias,
                       float* __restrict__ scal) {
    int j = threadIdx.x;  // 64 threads
    float v = tc[0] * wg[j] + tc[1] * wg[64 + j] + bg[j];
    float g = 1.0f / (1.0f + __expf(-v));
    for (int off = 32; off; off >>= 1) g += __shfl_xor(g, off, 64);
    if (j == 0) {
        scal[0] = 0.125f * (g * (1.0f / 64.0f));   // qscale (gate mean + 1/sqrt(64))
        scal[1] = sbias[0] * (1.0f - tc[0]);        // coef
    }
}

// ---------------- Kernel B: embed (h fp32; q,k,m bf16; st, sbi) ----------------
__global__ __launch_bounds__(256) void embed_k(
    const float* __restrict__ nf, const float* __restrict__ tc,
    const float* __restrict__ w1, const float* __restrict__ b1,
    const float* __restrict__ w2, const float* __restrict__ b2,
    const float* __restrict__ wq, const float* __restrict__ bq,
    const float* __restrict__ wk, const float* __restrict__ bk,
    const float* __restrict__ wm, const float* __restrict__ bm,
    float* __restrict__ ws)
{
    const int w = threadIdx.x >> 6, lane = threadIdx.x & 63;
    const int row = blockIdx.x * 4 + w;
    __shared__ float ts[4][64], hs[4][64];
    const float qscale = ws[WS_SCAL + 0];
    const float coef   = ws[WS_SCAL + 1];
    const float f0 = nf[row * 3], f1 = nf[row * 3 + 1], f2 = nf[row * 3 + 2];
    const float t0 = tc[0], t1 = tc[1];
    float v = b1[lane];
    v = fmaf(f0, w1[lane], v);
    v = fmaf(f1, w1[64 + lane], v);
    v = fmaf(f2, w1[128 + lane], v);
    v = fmaf(t0, w1[192 + lane], v);
    v = fmaf(t1, w1[256 + lane], v);
    ts[w][lane] = fmaxf(v, 0.0f);
    __syncthreads();
    float hv = b2[lane];
    #pragma unroll 8
    for (int j = 0; j < 64; j++) hv = fmaf(ts[w][j], w2[j * 64 + lane], hv);
    hs[w][lane] = hv;
    ws[WS_H + row * 64 + lane] = hv;
    __syncthreads();
    float qv = bq[lane], kv = bk[lane], mv = bm[lane];
    #pragma unroll 4
    for (int j = 0; j < 64; j++) {
        const float hj = hs[w][j];
        qv = fmaf(hj, wq[j * 64 + lane], qv);
        kv = fmaf(hj, wk[j * 64 + lane], kv);
        mv = fmaf(hj, wm[j * 64 + lane], mv);
    }
    u16* wu = (u16*)ws;
    wu[WU_QB + row * 64 + lane] = f2bf(qv * qscale);
    wu[WU_KB + row * 64 + lane] = f2bf(kv);
    wu[WU_MB + row * 64 + lane] = f2bf(mv);
    if (lane == 0) {
        ws[WS_ST + row]  = f2;
        ws[WS_SBI + row] = f2 * coef;
    }
}

// ---------------- Kernel B2: transpose M (bf16) ----------------
__global__ __launch_bounds__(256) void transp_k(float* __restrict__ ws) {
    const u16* mb = (const u16*)ws + WU_MB;
    u16* mt = (u16*)ws + WU_MT;
    __shared__ __align__(16) u16 tile[64][72];
    const int i0 = blockIdx.x * 64;
    const int t = threadIdx.x;
    {
        const int r = t >> 2, cb = (t & 3) * 16;
        *(uint4*)&tile[r][cb]     = *(const uint4*)&mb[(size_t)(i0 + r) * 64 + cb];
        *(uint4*)&tile[r][cb + 8] = *(const uint4*)&mb[(size_t)(i0 + r) * 64 + cb + 8];
    }
    __syncthreads();
    const int c = t >> 2, rb = (t & 3) * 16;
    u16 tmp[16];
    #pragma unroll
    for (int i = 0; i < 16; i++) tmp[i] = tile[rb + i][c];
    *(uint4*)&mt[(size_t)c * N + i0 + rb]     = *(uint4*)&tmp[0];
    *(uint4*)&mt[(size_t)c * N + i0 + rb + 8] = *(uint4*)&tmp[8];
}

// ---------------- Kernel C: MFMA streaming attention ----------------
// 4 waves, 64x64 tiles. K staged into LDS in PERMUTED row order so that
// S-column of lane n16 in MFMA-call ct = key n16*4+ct  ->  adj reads become
// dwordx4, st reads float4, P-writes ds_write_b64. K/M register pipeline is
// 2 tiles deep (load top of t for t+2, ds_write bottom of t+1): the vmcnt
// wait before the bottom barrier covers ~2 tile bodies >= HBM latency.
#define TILE_BODY(CUR, KL, KS_, ADJ, ST)                                      \
{                                                                             \
    /* top: issue K/M loads for tile t+2 into set KL */                       \
    const int jk = (jt + 128 < jend) ? (jt + 128) : (jend - 64);              \
    KL##0 = *(const uint4*)&kb[(size_t)(jk + psr) * 64 + scb];                \
    KL##1 = *(const uint4*)&kb[(size_t)(jk + psr) * 64 + scb + 8];            \
    KL##2 = *(const uint4*)&mt[(size_t)sr * N + jk + scb];                    \
    KL##3 = *(const uint4*)&mt[(size_t)sr * N + jk + scb + 8];                \
    /* S = Q K^T : 4 MFMA-pairs over column groups */                         \
    f32x4 s[4];                                                               \
    _Pragma("unroll")                                                         \
    for (int ct = 0; ct < 4; ct++) {                                          \
        const bf16x8 b0 = *(const bf16x8*)&ks[CUR][ct * 16 + n16][quad * 8];  \
        const bf16x8 b1 = *(const bf16x8*)&ks[CUR][ct * 16 + n16][32 + quad * 8]; \
        f32x4 sv = {0.f, 0.f, 0.f, 0.f};                                      \
        sv = __builtin_amdgcn_mfma_f32_16x16x32_bf16(aq0, b0, sv, 0, 0, 0);   \
        sv = __builtin_amdgcn_mfma_f32_16x16x32_bf16(aq1, b1, sv, 0, 0, 0);   \
        s[ct] = sv;                                                           \
    }                                                                         \
    /* epilogue: per row-reg pack 4 consecutive columns, write b64 */         \
    _Pragma("unroll")                                                         \
    for (int reg = 0; reg < 4; reg++) {                                       \
        ushort4 pw;                                                           \
        float p0, p1, p2, p3;                                                 \
        {                                                                     \
            const float a = ADJ[reg][0];                                      \
            p0 = __expf(s[0][reg] + (a == 0.0f ? NEGV : a) + sbr[reg] * ST[0]); \
        }                                                                     \
        {                                                                     \
            const float a = ADJ[reg][1];                                      \
            p1 = __expf(s[1][reg] + (a == 0.0f ? NEGV : a) + sbr[reg] * ST[1]); \
        }                                                                     \
        {                                                                     \
            const float a = ADJ[reg][2];                                      \
            p2 = __expf(s[2][reg] + (a == 0.0f ? NEGV : a) + sbr[reg] * ST[2]); \
        }                                                                     \
        {                                                                     \
            const float a = ADJ[reg][3];                                      \
            p3 = __expf(s[3][reg] + (a == 0.0f ? NEGV : a) + sbr[reg] * ST[3]); \
        }                                                                     \
        den[reg] += (p0 + p1) + (p2 + p3);                                    \
        pw.x = f2bf(p0); pw.y = f2bf(p1); pw.z = f2bf(p2); pw.w = f2bf(p3);   \
        *(ushort4*)&ps[m0 + quad * 4 + reg][n16 * 4] = pw;                    \
    }                                                                         \
    /* reload ADJ/ST with tile t+2 (just consumed; ~1.7 bodies to next use) */\
    {                                                                         \
        const int ja = (jt + 128 < jend) ? (jt + 128) : (jend - 64);          \
        _Pragma("unroll")                                                     \
        for (int reg = 0; reg < 4; reg++) {                                   \
            const float4 a4 = *(const float4*)&adj[(size_t)(i0 + m0 + quad * 4 + reg) * N + ja + n16 * 4]; \
            ADJ[reg][0] = a4.x; ADJ[reg][1] = a4.y;                           \
            ADJ[reg][2] = a4.z; ADJ[reg][3] = a4.w;                           \
        }                                                                     \
        const float4 s4 = *(const float4*)&st_g[ja + n16 * 4];                \
        ST[0] = s4.x; ST[1] = s4.y; ST[2] = s4.z; ST[3] = s4.w;               \
    }                                                                         \
    __syncthreads();                                                          \
    /* PV: acc += P(16x64) @ M(64x64) */                                      \
    {                                                                         \
        const bf16x8 ap0 = *(const bf16x8*)&ps[m0 + n16][quad * 8];           \
        const bf16x8 ap1 = *(const bf16x8*)&ps[m0 + n16][32 + quad * 8];      \
        _Pragma("unroll")                                                     \
        for (int nt = 0; nt < 4; nt++) {                                      \
            const bf16x8 b0 = *(const bf16x8*)&ms[CUR][nt * 16 + n16][quad * 8]; \
            const bf16x8 b1 = *(const bf16x8*)&ms[CUR][nt * 16 + n16][32 + quad * 8]; \
            acc[nt] = __builtin_amdgcn_mfma_f32_16x16x32_bf16(ap0, b0, acc[nt], 0, 0, 0); \
            acc[nt] = __builtin_amdgcn_mfma_f32_16x16x32_bf16(ap1, b1, acc[nt], 0, 0, 0); \
        }                                                                     \
    }                                                                         \
    /* ds_write K/M for t+1 (loaded 2 bodies ago -> vmcnt satisfied) */       \
    *(uint4*)&ks[1 - (CUR)][sr][scb]     = KS_##0;                            \
    *(uint4*)&ks[1 - (CUR)][sr][scb + 8] = KS_##1;                            \
    *(uint4*)&ms[1 - (CUR)][sr][scb]     = KS_##2;                            \
    *(uint4*)&ms[1 - (CUR)][sr][scb + 8] = KS_##3;                            \
    __syncthreads();                                                          \
    jt += 64;                                                                 \
}

__global__ __launch_bounds__(256, 3) void attn_k(const float* __restrict__ adj,
                                                 float* __restrict__ ws)
{
    const int rb = blockIdx.x, sp = blockIdx.y;
    const int i0 = rb * 64, j0 = sp * CPS;
    const int jend = j0 + CPS;
    const int tid = threadIdx.x;
    const int lane = tid & 63;
    const int quad = lane >> 4, n16 = lane & 15;
    const int m0 = (tid >> 6) * 16;

    __shared__ __align__(16) u16 ks[2][64][72];   // 18.4 KB (K, permuted rows)
    __shared__ __align__(16) u16 ms[2][64][72];   // 18.4 KB (M^T, standard)
    __shared__ __align__(16) u16 ps[64][76];      //  9.7 KB (P, standard key order)

    const u16* qb = (const u16*)ws + WU_QB;
    const u16* kb = (const u16*)ws + WU_KB;
    const u16* mt = (const u16*)ws + WU_MT;
    const float* st_g = ws + WS_ST;

    const int sr = tid >> 2, scb = (tid & 3) * 16;           // staging map
    const int psr = ((sr & 15) << 2) | (sr >> 4);            // permuted K row

    // 2-deep K/M pipeline registers (named -> no scratch)
    uint4 kmA0, kmA1, kmA2, kmA3, kmB0, kmB1, kmB2, kmB3;
    float adjA[4][4], adjB[4][4], stA[4], stB[4];

    // ---- prologue ----
    // km(tile0) -> LDS buf0 directly; km(tile1) -> kmB (stored bottom of t0)
    {
        const uint4 k0 = *(const uint4*)&kb[(size_t)(j0 + psr) * 64 + scb];
        const uint4 k1 = *(const uint4*)&kb[(size_t)(j0 + psr) * 64 + scb + 8];
        const uint4 q0 = *(const uint4*)&mt[(size_t)sr * N + j0 + scb];
        const uint4 q1 = *(const uint4*)&mt[(size_t)sr * N + j0 + scb + 8];
        const int j1 = j0 + 64;
        kmB0 = *(const uint4*)&kb[(size_t)(j1 + psr) * 64 + scb];
        kmB1 = *(const uint4*)&kb[(size_t)(j1 + psr) * 64 + scb + 8];
        kmB2 = *(const uint4*)&mt[(size_t)sr * N + j1 + scb];
        kmB3 = *(const uint4*)&mt[(size_t)sr * N + j1 + scb + 8];
        *(uint4*)&ks[0][sr][scb]     = k0;
        *(uint4*)&ks[0][sr][scb + 8] = k1;
        *(uint4*)&ms[0][sr][scb]     = q0;
        *(uint4*)&ms[0][sr][scb + 8] = q1;
    }
    // adj/st for tile0 -> A, tile1 -> B
    #pragma unroll
    for (int reg = 0; reg < 4; reg++) {
        const size_t rowb = (size_t)(i0 + m0 + quad * 4 + reg) * N + n16 * 4;
        const float4 a0 = *(const float4*)&adj[rowb + j0];
        adjA[reg][0] = a0.x; adjA[reg][1] = a0.y; adjA[reg][2] = a0.z; adjA[reg][3] = a0.w;
        const float4 a1 = *(const float4*)&adj[rowb + j0 + 64];
        adjB[reg][0] = a1.x; adjB[reg][1] = a1.y; adjB[reg][2] = a1.z; adjB[reg][3] = a1.w;
    }
    {
        const float4 s0 = *(const float4*)&st_g[j0 + n16 * 4];
        stA[0] = s0.x; stA[1] = s0.y; stA[2] = s0.z; stA[3] = s0.w;
        const float4 s1 = *(const float4*)&st_g[j0 + 64 + n16 * 4];
        stB[0] = s1.x; stB[1] = s1.y; stB[2] = s1.z; stB[3] = s1.w;
    }

    // Q fragments + per-row sb values from global
    const bf16x8 aq0 = *(const bf16x8*)&qb[(size_t)(i0 + m0 + n16) * 64 + quad * 8];
    const bf16x8 aq1 = *(const bf16x8*)&qb[(size_t)(i0 + m0 + n16) * 64 + 32 + quad * 8];
    float sbr[4];
    #pragma unroll
    for (int v = 0; v < 4; v++) sbr[v] = ws[WS_SBI + i0 + m0 + quad * 4 + v];

    f32x4 acc[4];
    #pragma unroll
    for (int i = 0; i < 4; i++) acc[i] = (f32x4){0.f, 0.f, 0.f, 0.f};
    float den[4] = {0.f, 0.f, 0.f, 0.f};

    __syncthreads();

    int jt = j0;
    for (int t = 0; t < NTILE; t += 2) {
        TILE_BODY(0, kmA, kmB, adjA, stA)   // even: load kmA(t+2), store kmB(t+1)
        TILE_BODY(1, kmB, kmA, adjB, stB)   // odd:  load kmB(t+2), store kmA(t+1)
    }

    // write agg partials (C-layout rows) + reduced denominators
    float* aggp = ws + WS_AGG + (size_t)sp * N * 64;
    #pragma unroll
    for (int nt = 0; nt < 4; nt++) {
        #pragma unroll
        for (int reg = 0; reg < 4; reg++) {
            aggp[(size_t)(i0 + m0 + quad * 4 + reg) * 64 + nt * 16 + n16] = acc[nt][reg];
        }
    }
    #pragma unroll
    for (int reg = 0; reg < 4; reg++) {
        float d = den[reg];
        d += __shfl_xor(d, 1, 64);
        d += __shfl_xor(d, 2, 64);
        d += __shfl_xor(d, 4, 64);
        d += __shfl_xor(d, 8, 64);
        if (n16 == 0) ws[WS_DEN + sp * N + i0 + m0 + quad * 4 + reg] = d;
    }
}

// ---------------- Kernel D: combine + LayerNorm + final MLP ----------------
__global__ __launch_bounds__(256) void final_k(
    const float* __restrict__ sa, const float* __restrict__ ln_g,
    const float* __restrict__ ln_b,
    const float* __restrict__ wa1, const float* __restrict__ ba1,
    const float* __restrict__ wa2, const float* __restrict__ ba2,
    const float* __restrict__ ws, float* __restrict__ out)
{
    const int w = threadIdx.x >> 6, lane = threadIdx.x & 63;
    const int row = blockIdx.x * 4 + w;
    __shared__ float es[4][64], hs2[4][64];
    float a = 0.0f;
    #pragma unroll
    for (int sp = 0; sp < NSPLIT; sp++)
        a += ws[WS_AGG + (size_t)sp * N * 64 + (size_t)row * 64 + lane];
    float d = 0.0f;
    #pragma unroll
    for (int sp = 0; sp < NSPLIT; sp++) d += ws[WS_DEN + sp * N + row];
    const float z = ws[WS_H + row * 64 + lane] + a / d;
    float mu = z;
    for (int off = 32; off; off >>= 1) mu += __shfl_xor(mu, off, 64);
    mu *= (1.0f / 64.0f);
    const float zc = z - mu;
    float var = zc * zc;
    for (int off = 32; off; off >>= 1) var += __shfl_xor(var, off, 64);
    var *= (1.0f / 64.0f);
    const float emb = zc * rsqrtf(var + EPSV) * ln_g[lane] + ln_b[lane];
    es[w][lane] = emb;
    __syncthreads();
    const float sa0 = sa[row * 2], sa1 = sa[row * 2 + 1];
    float hv = ba1[lane];
    #pragma unroll 8
    for (int c = 0; c < 64; c++) hv = fmaf(es[w][c], wa1[c * 64 + lane], hv);
    hv = fmaf(sa0, wa1[64 * 64 + lane], hv);
    hv = fmaf(sa1, wa1[65 * 64 + lane], hv);
    hs2[w][lane] = fmaxf(hv, 0.0f);
    __syncthreads();
    if (lane < 3) {
        float o = ba2[lane];
        for (int u = 0; u < 64; u++) o = fmaf(hs2[w][u], wa2[u * 3 + lane], o);
        out[row * 3 + lane] = o;
    }
}

extern "C" void kernel_launch(void* const* d_in, const int* in_sizes, int n_in,
                              void* d_out, int out_size, void* d_ws, size_t ws_size,
                              hipStream_t stream)
{
    const float* nf  = (const float*)d_in[0];
    const float* adj = (const float*)d_in[1];
    const float* tc  = (const float*)d_in[2];
    const float* sa  = (const float*)d_in[3];
    const float* w1  = (const float*)d_in[4];
    const float* b1  = (const float*)d_in[5];
    const float* w2  = (const float*)d_in[6];
    const float* b2  = (const float*)d_in[7];
    const float* wq  = (const float*)d_in[8];
    const float* bq  = (const float*)d_in[9];
    const float* wk  = (const float*)d_in[10];
    const float* bk  = (const float*)d_in[11];
    const float* wg  = (const float*)d_in[12];
    const float* bg  = (const float*)d_in[13];
    const float* sb  = (const float*)d_in[14];
    const float* wm  = (const float*)d_in[15];
    const float* bm  = (const float*)d_in[16];
    const float* lng = (const float*)d_in[17];
    const float* lnb = (const float*)d_in[18];
    const float* wa1 = (const float*)d_in[19];
    const float* ba1 = (const float*)d_in[20];
    const float* wa2 = (const float*)d_in[21];
    const float* ba2 = (const float*)d_in[22];
    float* ws  = (float*)d_ws;
    float* out = (float*)d_out;

    prep_k<<<1, 64, 0, stream>>>(tc, wg, bg, sb, ws + WS_SCAL);
    embed_k<<<N / 4, 256, 0, stream>>>(nf, tc, w1, b1, w2, b2, wq, bq, wk, bk,
                                       wm, bm, ws);
    transp_k<<<N / 64, 256, 0, stream>>>(ws);
    attn_k<<<dim3(N / 64, NSPLIT), 256, 0, stream>>>(adj, ws);
    final_k<<<N / 4, 256, 0, stream>>>(sa, lng, lnb, wa1, ba1, wa2, ba2, ws, out);
}

// Round 7
// 502.488 us; speedup vs baseline: 1.0429x; 1.0429x over previous
//
#include <hip/hip_runtime.h>
#include <hip/hip_bf16.h>
#include <math.h>

#define N 8192
#define NEGV -1000000000.0f
#define EPSV 1e-05f
#define NSPLIT 8
#define CPS (N / NSPLIT)   // 1024 columns per split
#define NTILE (CPS / 64)   // 16 tiles

typedef short bf16x8 __attribute__((ext_vector_type(8)));
typedef float f32x4 __attribute__((ext_vector_type(4)));
typedef unsigned short u16;

// ---- float workspace layout ----
#define WS_SCAL 0
#define WS_H    64                        // N*64 fp32
#define WS_ST   (WS_H + N * 64)           // N
#define WS_SBI  (WS_ST + N)               // N
#define WS_DEN  (WS_SBI + N)              // NSPLIT*N
#define WS_AGG  (WS_DEN + NSPLIT * N)     // NSPLIT*N*64
#define WS_F_END (WS_AGG + NSPLIT * N * 64)
// ---- u16 (bf16) region, offsets in u16 units from (u16*)ws ----
#define WU_BASE (WS_F_END * 2)
#define WU_QB (WU_BASE)                   // N*64  q row-major
#define WU_KF (WU_BASE + N * 64)          // N*64  K in MFMA-B fragment order
#define WU_MB (WU_BASE + 2 * N * 64)      // N*64  m row-major (repacked below)
#define WU_MF (WU_BASE + 3 * N * 64)      // N*64  M in MFMA-B fragment order

static __device__ __forceinline__ u16 f2bf(float f) {
    __hip_bfloat16 h = __float2bfloat16(f);
    return *(u16*)&h;
}

// ---------------- Kernel A: scalar prep ----------------
__global__ void prep_k(const float* __restrict__ tc, const float* __restrict__ wg,
                       const float* __restrict__ bg, const float* __restrict__ sbias,
                       float* __restrict__ scal) {
    int j = threadIdx.x;  // 64 threads
    float v = tc[0] * wg[j] + tc[1] * wg[64 + j] + bg[j];
    float g = 1.0f / (1.0f + __expf(-v));
    for (int off = 32; off; off >>= 1) g += __shfl_xor(g, off, 64);
    if (j == 0) {
        scal[0] = 0.125f * (g * (1.0f / 64.0f));   // qscale (gate mean + 1/sqrt(64))
        scal[1] = sbias[0] * (1.0f - tc[0]);        // coef
    }
}

// ---------------- Kernel B: embed ----------------
// h fp32 row-major; q bf16 row-major; K bf16 in FRAGMENT order
// (chunk = ((((key/64)*4 + key&3)*2 + feat/32)*4 + (feat/8)&3)*16 + (key&63)/4,
//  element j = feat&7) so attn B-frag loads are lane-consecutive; m row-major.
__global__ __launch_bounds__(256) void embed_k(
    const float* __restrict__ nf, const float* __restrict__ tc,
    const float* __restrict__ w1, const float* __restrict__ b1,
    const float* __restrict__ w2, const float* __restrict__ b2,
    const float* __restrict__ wq, const float* __restrict__ bq,
    const float* __restrict__ wk, const float* __restrict__ bk,
    const float* __restrict__ wm, const float* __restrict__ bm,
    float* __restrict__ ws)
{
    const int w = threadIdx.x >> 6, lane = threadIdx.x & 63;
    const int row = blockIdx.x * 4 + w;
    __shared__ float ts[4][64], hs[4][64];
    const float qscale = ws[WS_SCAL + 0];
    const float coef   = ws[WS_SCAL + 1];
    const float f0 = nf[row * 3], f1 = nf[row * 3 + 1], f2 = nf[row * 3 + 2];
    const float t0 = tc[0], t1 = tc[1];
    float v = b1[lane];
    v = fmaf(f0, w1[lane], v);
    v = fmaf(f1, w1[64 + lane], v);
    v = fmaf(f2, w1[128 + lane], v);
    v = fmaf(t0, w1[192 + lane], v);
    v = fmaf(t1, w1[256 + lane], v);
    ts[w][lane] = fmaxf(v, 0.0f);
    __syncthreads();
    float hv = b2[lane];
    #pragma unroll 8
    for (int j = 0; j < 64; j++) hv = fmaf(ts[w][j], w2[j * 64 + lane], hv);
    hs[w][lane] = hv;
    ws[WS_H + row * 64 + lane] = hv;
    __syncthreads();
    float qv = bq[lane], kv = bk[lane], mv = bm[lane];
    #pragma unroll 4
    for (int j = 0; j < 64; j++) {
        const float hj = hs[w][j];
        qv = fmaf(hj, wq[j * 64 + lane], qv);
        kv = fmaf(hj, wk[j * 64 + lane], kv);
        mv = fmaf(hj, wm[j * 64 + lane], mv);
    }
    u16* wu = (u16*)ws;
    wu[WU_QB + row * 64 + lane] = f2bf(qv * qscale);
    // K fragment-order scatter (key=row, feat=lane)
    {
        const size_t kb4 = row >> 6;
        const int ct = row & 3, n16r = (row & 63) >> 2;
        const int half = lane >> 5, quadl = (lane >> 3) & 3, jl = lane & 7;
        const size_t flat = ((((kb4 * 4 + ct) * 2 + half) * 4 + quadl) * 16 + n16r) * 8 + jl;
        wu[WU_KF + flat] = f2bf(kv);
    }
    wu[WU_MB + row * 64 + lane] = f2bf(mv);
    if (lane == 0) {
        ws[WS_ST + row]  = f2;
        ws[WS_SBI + row] = f2 * coef;
    }
}

// ---------------- Kernel B2: repack M into MFMA-B fragment order ----------------
// chunk c in key-block jb: c = ((nt*2+half)*4+quad)*16+n16 holds
// M[key=jb*64+half*32+quad*8+j][ch=nt*16+n16], j=0..7.
__global__ __launch_bounds__(256) void mfrag_k(float* __restrict__ ws) {
    const u16* mb = (const u16*)ws + WU_MB;
    u16* mf = (u16*)ws + WU_MF;
    __shared__ __align__(16) u16 tile[64][72];
    const int jb = blockIdx.x;
    const int t = threadIdx.x;
    {
        const int r = t >> 2, cb = (t & 3) * 16;
        *(uint4*)&tile[r][cb]     = *(const uint4*)&mb[(size_t)(jb * 64 + r) * 64 + cb];
        *(uint4*)&tile[r][cb + 8] = *(const uint4*)&mb[(size_t)(jb * 64 + r) * 64 + cb + 8];
    }
    __syncthreads();
    #pragma unroll
    for (int cc = 0; cc < 2; cc++) {
        const int c = t * 2 + cc;                        // 0..511
        const int n16 = c & 15, quad = (c >> 4) & 3;
        const int half = (c >> 6) & 1, nt = c >> 7;
        u16 tmp[8];
        #pragma unroll
        for (int j = 0; j < 8; j++) tmp[j] = tile[half * 32 + quad * 8 + j][nt * 16 + n16];
        *(uint4*)&mf[(size_t)jb * 4096 + (size_t)c * 8] = *(uint4*)&tmp[0];
    }
}

// ---------------- Kernel C: BARRIER-FREE MFMA streaming attention ----------------
// P is wave-private (each wave writes and reads only ps rows m0..m0+15), so the
// K-loop has no __syncthreads at all. K and M B-fragments are read directly from
// global in fragment order (lane-consecutive 16B -> coalesced, L2-resident).
// Column permutation: S-column n16*4+ct -> adj reads are float4, P writes b64.
__global__ __launch_bounds__(256, 4) void attn_k(const float* __restrict__ adj,
                                                 float* __restrict__ ws)
{
    const int rb = blockIdx.x, sp = blockIdx.y;
    const int i0 = rb * 64, j0 = sp * CPS;
    const int tid = threadIdx.x;
    const int lane = tid & 63;
    const int quad = lane >> 4, n16 = lane & 15;
    const int m0 = (tid >> 6) * 16;

    __shared__ __align__(16) u16 ps[64][76];   // 9.7 KB, wave-private quarters

    const u16* qb = (const u16*)ws + WU_QB;
    const u16* kf = (const u16*)ws + WU_KF;
    const u16* mf = (const u16*)ws + WU_MF;
    const float* st_g = ws + WS_ST;

    // Q fragments (A-layout) + per-row sb values
    const bf16x8 aq0 = *(const bf16x8*)&qb[(size_t)(i0 + m0 + n16) * 64 + quad * 8];
    const bf16x8 aq1 = *(const bf16x8*)&qb[(size_t)(i0 + m0 + n16) * 64 + 32 + quad * 8];
    float sbr[4];
    #pragma unroll
    for (int v = 0; v < 4; v++) sbr[v] = ws[WS_SBI + i0 + m0 + quad * 4 + v];

    f32x4 acc[4];
    #pragma unroll
    for (int i = 0; i < 4; i++) acc[i] = (f32x4){0.f, 0.f, 0.f, 0.f};
    float den[4] = {0.f, 0.f, 0.f, 0.f};

    const int fragoff = (quad * 16 + n16) * 8;   // lane's 16B slot within a half-group

    #pragma unroll 2
    for (int t = 0; t < NTILE; t++) {
        const int jt = j0 + t * 64;
        const u16* kfb = kf + (size_t)(jt >> 6) * 4096;
        const u16* mfb = mf + (size_t)(jt >> 6) * 4096;

        // adj + st for this tile (coalesced float4)
        float4 aa[4];
        #pragma unroll
        for (int reg = 0; reg < 4; reg++)
            aa[reg] = *(const float4*)&adj[(size_t)(i0 + m0 + quad * 4 + reg) * N + jt + n16 * 4];
        const float4 st4 = *(const float4*)&st_g[jt + n16 * 4];

        // S = Q K^T : B-frags straight from fragment-order global (L2)
        f32x4 s[4];
        #pragma unroll
        for (int ct = 0; ct < 4; ct++) {
            const bf16x8 b0 = *(const bf16x8*)&kfb[(ct * 2 + 0) * 512 + fragoff];
            const bf16x8 b1 = *(const bf16x8*)&kfb[(ct * 2 + 1) * 512 + fragoff];
            f32x4 sv = {0.f, 0.f, 0.f, 0.f};
            sv = __builtin_amdgcn_mfma_f32_16x16x32_bf16(aq0, b0, sv, 0, 0, 0);
            sv = __builtin_amdgcn_mfma_f32_16x16x32_bf16(aq1, b1, sv, 0, 0, 0);
            s[ct] = sv;
        }

        // epilogue: column of call ct = key n16*4+ct -> pack b64 P writes
        #pragma unroll
        for (int reg = 0; reg < 4; reg++) {
            const float sb_r = sbr[reg];
            float a0 = aa[reg].x, a1 = aa[reg].y, a2 = aa[reg].z, a3 = aa[reg].w;
            const float p0 = __expf(s[0][reg] + (a0 == 0.0f ? NEGV : a0) + sb_r * st4.x);
            const float p1 = __expf(s[1][reg] + (a1 == 0.0f ? NEGV : a1) + sb_r * st4.y);
            const float p2 = __expf(s[2][reg] + (a2 == 0.0f ? NEGV : a2) + sb_r * st4.z);
            const float p3 = __expf(s[3][reg] + (a3 == 0.0f ? NEGV : a3) + sb_r * st4.w);
            den[reg] += (p0 + p1) + (p2 + p3);
            ushort4 pw;
            pw.x = f2bf(p0); pw.y = f2bf(p1); pw.z = f2bf(p2); pw.w = f2bf(p3);
            *(ushort4*)&ps[m0 + quad * 4 + reg][n16 * 4] = pw;
        }

        // PV: A-frags from wave-private ps (lgkm wait only, no barrier)
        const bf16x8 ap0 = *(const bf16x8*)&ps[m0 + n16][quad * 8];
        const bf16x8 ap1 = *(const bf16x8*)&ps[m0 + n16][32 + quad * 8];
        #pragma unroll
        for (int nt = 0; nt < 4; nt++) {
            const bf16x8 b0 = *(const bf16x8*)&mfb[(nt * 2 + 0) * 512 + fragoff];
            const bf16x8 b1 = *(const bf16x8*)&mfb[(nt * 2 + 1) * 512 + fragoff];
            acc[nt] = __builtin_amdgcn_mfma_f32_16x16x32_bf16(ap0, b0, acc[nt], 0, 0, 0);
            acc[nt] = __builtin_amdgcn_mfma_f32_16x16x32_bf16(ap1, b1, acc[nt], 0, 0, 0);
        }
    }

    // write agg partials (C-layout rows) + reduced denominators
    float* aggp = ws + WS_AGG + (size_t)sp * N * 64;
    #pragma unroll
    for (int nt = 0; nt < 4; nt++) {
        #pragma unroll
        for (int reg = 0; reg < 4; reg++) {
            aggp[(size_t)(i0 + m0 + quad * 4 + reg) * 64 + nt * 16 + n16] = acc[nt][reg];
        }
    }
    #pragma unroll
    for (int reg = 0; reg < 4; reg++) {
        float d = den[reg];
        d += __shfl_xor(d, 1, 64);
        d += __shfl_xor(d, 2, 64);
        d += __shfl_xor(d, 4, 64);
        d += __shfl_xor(d, 8, 64);
        if (n16 == 0) ws[WS_DEN + sp * N + i0 + m0 + quad * 4 + reg] = d;
    }
}

// ---------------- Kernel D: combine + LayerNorm + final MLP ----------------
__global__ __launch_bounds__(256) void final_k(
    const float* __restrict__ sa, const float* __restrict__ ln_g,
    const float* __restrict__ ln_b,
    const float* __restrict__ wa1, const float* __restrict__ ba1,
    const float* __restrict__ wa2, const float* __restrict__ ba2,
    const float* __restrict__ ws, float* __restrict__ out)
{
    const int w = threadIdx.x >> 6, lane = threadIdx.x & 63;
    const int row = blockIdx.x * 4 + w;
    __shared__ float es[4][64], hs2[4][64];
    float a = 0.0f;
    #pragma unroll
    for (int sp = 0; sp < NSPLIT; sp++)
        a += ws[WS_AGG + (size_t)sp * N * 64 + (size_t)row * 64 + lane];
    float d = 0.0f;
    #pragma unroll
    for (int sp = 0; sp < NSPLIT; sp++) d += ws[WS_DEN + sp * N + row];
    const float z = ws[WS_H + row * 64 + lane] + a / d;
    float mu = z;
    for (int off = 32; off; off >>= 1) mu += __shfl_xor(mu, off, 64);
    mu *= (1.0f / 64.0f);
    const float zc = z - mu;
    float var = zc * zc;
    for (int off = 32; off; off >>= 1) var += __shfl_xor(var, off, 64);
    var *= (1.0f / 64.0f);
    const float emb = zc * rsqrtf(var + EPSV) * ln_g[lane] + ln_b[lane];
    es[w][lane] = emb;
    __syncthreads();
    const float sa0 = sa[row * 2], sa1 = sa[row * 2 + 1];
    float hv = ba1[lane];
    #pragma unroll 8
    for (int c = 0; c < 64; c++) hv = fmaf(es[w][c], wa1[c * 64 + lane], hv);
    hv = fmaf(sa0, wa1[64 * 64 + lane], hv);
    hv = fmaf(sa1, wa1[65 * 64 + lane], hv);
    hs2[w][lane] = fmaxf(hv, 0.0f);
    __syncthreads();
    if (lane < 3) {
        float o = ba2[lane];
        for (int u = 0; u < 64; u++) o = fmaf(hs2[w][u], wa2[u * 3 + lane], o);
        out[row * 3 + lane] = o;
    }
}

extern "C" void kernel_launch(void* const* d_in, const int* in_sizes, int n_in,
                              void* d_out, int out_size, void* d_ws, size_t ws_size,
                              hipStream_t stream)
{
    const float* nf  = (const float*)d_in[0];
    const float* adj = (const float*)d_in[1];
    const float* tc  = (const float*)d_in[2];
    const float* sa  = (const float*)d_in[3];
    const float* w1  = (const float*)d_in[4];
    const float* b1  = (const float*)d_in[5];
    const float* w2  = (const float*)d_in[6];
    const float* b2  = (const float*)d_in[7];
    const float* wq  = (const float*)d_in[8];
    const float* bq  = (const float*)d_in[9];
    const float* wk  = (const float*)d_in[10];
    const float* bk  = (const float*)d_in[11];
    const float* wg  = (const float*)d_in[12];
    const float* bg  = (const float*)d_in[13];
    const float* sb  = (const float*)d_in[14];
    const float* wm  = (const float*)d_in[15];
    const float* bm  = (const float*)d_in[16];
    const float* lng = (const float*)d_in[17];
    const float* lnb = (const float*)d_in[18];
    const float* wa1 = (const float*)d_in[19];
    const float* ba1 = (const float*)d_in[20];
    const float* wa2 = (const float*)d_in[21];
    const float* ba2 = (const float*)d_in[22];
    float* ws  = (float*)d_ws;
    float* out = (float*)d_out;

    prep_k<<<1, 64, 0, stream>>>(tc, wg, bg, sb, ws + WS_SCAL);
    embed_k<<<N / 4, 256, 0, stream>>>(nf, tc, w1, b1, w2, b2, wq, bq, wk, bk,
                                       wm, bm, ws);
    mfrag_k<<<N / 64, 256, 0, stream>>>(ws);
    attn_k<<<dim3(N / 64, NSPLIT), 256, 0, stream>>>(adj, ws);
    final_k<<<N / 4, 256, 0, stream>>>(sa, lng, lnb, wa1, ba1, wa2, ba2, ws, out);
}

// Round 8
// 487.534 us; speedup vs baseline: 1.0749x; 1.0307x over previous
//
#include <hip/hip_runtime.h>
#include <hip/hip_bf16.h>
#include <math.h>

#define N 8192
#define NEGV -1000000000.0f
#define EPSV 1e-05f
#define NSPLIT 16
#define CPS (N / NSPLIT)   // 512 columns per split
#define NTILE (CPS / 64)   // 8 tiles

typedef short bf16x8 __attribute__((ext_vector_type(8)));
typedef float f32x4 __attribute__((ext_vector_type(4)));
typedef unsigned short u16;

// ---- float workspace layout ----
#define WS_SCAL 0
#define WS_H    64                        // N*64 fp32
#define WS_ST   (WS_H + N * 64)           // N
#define WS_SBI  (WS_ST + N)               // N
#define WS_DEN  (WS_SBI + N)              // NSPLIT*N
#define WS_AGG  (WS_DEN + NSPLIT * N)     // NSPLIT*N*64
#define WS_F_END (WS_AGG + NSPLIT * N * 64)
// ---- u16 (bf16) region, offsets in u16 units from (u16*)ws ----
#define WU_BASE (WS_F_END * 2)
#define WU_QB (WU_BASE)                   // N*64  q row-major
#define WU_KF (WU_BASE + N * 64)          // N*64  K in MFMA-B fragment order
#define WU_MB (WU_BASE + 2 * N * 64)      // N*64  m row-major (repacked below)
#define WU_MF (WU_BASE + 3 * N * 64)      // N*64  M in MFMA-B fragment order

static __device__ __forceinline__ u16 f2bf(float f) {
    __hip_bfloat16 h = __float2bfloat16(f);
    return *(u16*)&h;
}
static __device__ __forceinline__ f32x4 ntload4(const float* p) {
    return __builtin_nontemporal_load((const f32x4*)p);
}

// ---------------- Kernel A: scalar prep ----------------
__global__ void prep_k(const float* __restrict__ tc, const float* __restrict__ wg,
                       const float* __restrict__ bg, const float* __restrict__ sbias,
                       float* __restrict__ scal) {
    int j = threadIdx.x;  // 64 threads
    float v = tc[0] * wg[j] + tc[1] * wg[64 + j] + bg[j];
    float g = 1.0f / (1.0f + __expf(-v));
    for (int off = 32; off; off >>= 1) g += __shfl_xor(g, off, 64);
    if (j == 0) {
        scal[0] = 0.125f * (g * (1.0f / 64.0f));   // qscale (gate mean + 1/sqrt(64))
        scal[1] = sbias[0] * (1.0f - tc[0]);        // coef
    }
}

// ---------------- Kernel B: embed ----------------
// h fp32 row-major; q bf16 row-major; K bf16 in FRAGMENT order; m row-major.
__global__ __launch_bounds__(256) void embed_k(
    const float* __restrict__ nf, const float* __restrict__ tc,
    const float* __restrict__ w1, const float* __restrict__ b1,
    const float* __restrict__ w2, const float* __restrict__ b2,
    const float* __restrict__ wq, const float* __restrict__ bq,
    const float* __restrict__ wk, const float* __restrict__ bk,
    const float* __restrict__ wm, const float* __restrict__ bm,
    float* __restrict__ ws)
{
    const int w = threadIdx.x >> 6, lane = threadIdx.x & 63;
    const int row = blockIdx.x * 4 + w;
    __shared__ float ts[4][64], hs[4][64];
    const float qscale = ws[WS_SCAL + 0];
    const float coef   = ws[WS_SCAL + 1];
    const float f0 = nf[row * 3], f1 = nf[row * 3 + 1], f2 = nf[row * 3 + 2];
    const float t0 = tc[0], t1 = tc[1];
    float v = b1[lane];
    v = fmaf(f0, w1[lane], v);
    v = fmaf(f1, w1[64 + lane], v);
    v = fmaf(f2, w1[128 + lane], v);
    v = fmaf(t0, w1[192 + lane], v);
    v = fmaf(t1, w1[256 + lane], v);
    ts[w][lane] = fmaxf(v, 0.0f);
    __syncthreads();
    float hv = b2[lane];
    #pragma unroll 8
    for (int j = 0; j < 64; j++) hv = fmaf(ts[w][j], w2[j * 64 + lane], hv);
    hs[w][lane] = hv;
    ws[WS_H + row * 64 + lane] = hv;
    __syncthreads();
    float qv = bq[lane], kv = bk[lane], mv = bm[lane];
    #pragma unroll 4
    for (int j = 0; j < 64; j++) {
        const float hj = hs[w][j];
        qv = fmaf(hj, wq[j * 64 + lane], qv);
        kv = fmaf(hj, wk[j * 64 + lane], kv);
        mv = fmaf(hj, wm[j * 64 + lane], mv);
    }
    u16* wu = (u16*)ws;
    wu[WU_QB + row * 64 + lane] = f2bf(qv * qscale);
    // K fragment-order scatter (key=row, feat=lane)
    {
        const size_t kb4 = row >> 6;
        const int ct = row & 3, n16r = (row & 63) >> 2;
        const int half = lane >> 5, quadl = (lane >> 3) & 3, jl = lane & 7;
        const size_t flat = ((((kb4 * 4 + ct) * 2 + half) * 4 + quadl) * 16 + n16r) * 8 + jl;
        wu[WU_KF + flat] = f2bf(kv);
    }
    wu[WU_MB + row * 64 + lane] = f2bf(mv);
    if (lane == 0) {
        ws[WS_ST + row]  = f2;
        ws[WS_SBI + row] = f2 * coef;
    }
}

// ---------------- Kernel B2: repack M into MFMA-B fragment order ----------------
__global__ __launch_bounds__(256) void mfrag_k(float* __restrict__ ws) {
    const u16* mb = (const u16*)ws + WU_MB;
    u16* mf = (u16*)ws + WU_MF;
    __shared__ __align__(16) u16 tile[64][72];
    const int jb = blockIdx.x;
    const int t = threadIdx.x;
    {
        const int r = t >> 2, cb = (t & 3) * 16;
        *(uint4*)&tile[r][cb]     = *(const uint4*)&mb[(size_t)(jb * 64 + r) * 64 + cb];
        *(uint4*)&tile[r][cb + 8] = *(const uint4*)&mb[(size_t)(jb * 64 + r) * 64 + cb + 8];
    }
    __syncthreads();
    #pragma unroll
    for (int cc = 0; cc < 2; cc++) {
        const int c = t * 2 + cc;                        // 0..511
        const int n16 = c & 15, quad = (c >> 4) & 3;
        const int half = (c >> 6) & 1, nt = c >> 7;
        u16 tmp[8];
        #pragma unroll
        for (int j = 0; j < 8; j++) tmp[j] = tile[half * 32 + quad * 8 + j][nt * 16 + n16];
        *(uint4*)&mf[(size_t)jb * 4096 + (size_t)c * 8] = *(uint4*)&tmp[0];
    }
}

// ---------------- Kernel C: barrier-free MFMA attention + NT adj stream ----------------
// adj is pure streaming (zero reuse): non-temporal loads keep it from evicting
// the 2 MB of K/M/Q fragments out of L2 -> fragment loads become L2 hits.
// adj/st prefetched one tile ahead in named registers (distance-1 pipeline).
__global__ __launch_bounds__(256, 4) void attn_k(const float* __restrict__ adj,
                                                 float* __restrict__ ws)
{
    const int rb = blockIdx.x, sp = blockIdx.y;
    const int i0 = rb * 64, j0 = sp * CPS;
    const int tid = threadIdx.x;
    const int lane = tid & 63;
    const int quad = lane >> 4, n16 = lane & 15;
    const int m0 = (tid >> 6) * 16;

    __shared__ __align__(16) u16 ps[64][76];   // 9.7 KB, wave-private quarters

    const u16* qb = (const u16*)ws + WU_QB;
    const u16* kf = (const u16*)ws + WU_KF;
    const u16* mf = (const u16*)ws + WU_MF;
    const float* st_g = ws + WS_ST;

    // Q fragments (A-layout) + per-row sb values
    const bf16x8 aq0 = *(const bf16x8*)&qb[(size_t)(i0 + m0 + n16) * 64 + quad * 8];
    const bf16x8 aq1 = *(const bf16x8*)&qb[(size_t)(i0 + m0 + n16) * 64 + 32 + quad * 8];
    float sbr[4];
    #pragma unroll
    for (int v = 0; v < 4; v++) sbr[v] = ws[WS_SBI + i0 + m0 + quad * 4 + v];

    f32x4 acc[4];
    #pragma unroll
    for (int i = 0; i < 4; i++) acc[i] = (f32x4){0.f, 0.f, 0.f, 0.f};
    float den[4] = {0.f, 0.f, 0.f, 0.f};

    const int fragoff = (quad * 16 + n16) * 8;   // lane's 16B slot within a half-group
    const size_t arow0 = (size_t)(i0 + m0 + quad * 4 + 0) * N + n16 * 4;
    const size_t arow1 = (size_t)(i0 + m0 + quad * 4 + 1) * N + n16 * 4;
    const size_t arow2 = (size_t)(i0 + m0 + quad * 4 + 2) * N + n16 * 4;
    const size_t arow3 = (size_t)(i0 + m0 + quad * 4 + 3) * N + n16 * 4;

    // prime the distance-1 adj/st pipeline with tile 0
    f32x4 aaC0 = ntload4(&adj[arow0 + j0]);
    f32x4 aaC1 = ntload4(&adj[arow1 + j0]);
    f32x4 aaC2 = ntload4(&adj[arow2 + j0]);
    f32x4 aaC3 = ntload4(&adj[arow3 + j0]);
    f32x4 stC  = *(const f32x4*)&st_g[j0 + n16 * 4];

    #pragma unroll 2
    for (int t = 0; t < NTILE; t++) {
        const int jt = j0 + t * 64;
        const int jn = j0 + ((t + 1 < NTILE) ? (t + 1) : t) * 64;
        const u16* kfb = kf + (size_t)(jt >> 6) * 4096;
        const u16* mfb = mf + (size_t)(jt >> 6) * 4096;

        // prefetch adj/st for tile t+1 (HBM latency hidden under this tile)
        const f32x4 aaN0 = ntload4(&adj[arow0 + jn]);
        const f32x4 aaN1 = ntload4(&adj[arow1 + jn]);
        const f32x4 aaN2 = ntload4(&adj[arow2 + jn]);
        const f32x4 aaN3 = ntload4(&adj[arow3 + jn]);
        const f32x4 stN  = *(const f32x4*)&st_g[jn + n16 * 4];

        // S = Q K^T : B-frags from fragment-order global (L2-resident)
        f32x4 s[4];
        #pragma unroll
        for (int ct = 0; ct < 4; ct++) {
            const bf16x8 b0 = *(const bf16x8*)&kfb[(ct * 2 + 0) * 512 + fragoff];
            const bf16x8 b1 = *(const bf16x8*)&kfb[(ct * 2 + 1) * 512 + fragoff];
            f32x4 sv = {0.f, 0.f, 0.f, 0.f};
            sv = __builtin_amdgcn_mfma_f32_16x16x32_bf16(aq0, b0, sv, 0, 0, 0);
            sv = __builtin_amdgcn_mfma_f32_16x16x32_bf16(aq1, b1, sv, 0, 0, 0);
            s[ct] = sv;
        }

        // epilogue: column of call ct = key n16*4+ct -> pack b64 P writes
        {
            const float p00 = __expf(s[0][0] + (aaC0.x == 0.0f ? NEGV : aaC0.x) + sbr[0] * stC.x);
            const float p01 = __expf(s[1][0] + (aaC0.y == 0.0f ? NEGV : aaC0.y) + sbr[0] * stC.y);
            const float p02 = __expf(s[2][0] + (aaC0.z == 0.0f ? NEGV : aaC0.z) + sbr[0] * stC.z);
            const float p03 = __expf(s[3][0] + (aaC0.w == 0.0f ? NEGV : aaC0.w) + sbr[0] * stC.w);
            den[0] += (p00 + p01) + (p02 + p03);
            ushort4 pw; pw.x = f2bf(p00); pw.y = f2bf(p01); pw.z = f2bf(p02); pw.w = f2bf(p03);
            *(ushort4*)&ps[m0 + quad * 4 + 0][n16 * 4] = pw;
        }
        {
            const float p10 = __expf(s[0][1] + (aaC1.x == 0.0f ? NEGV : aaC1.x) + sbr[1] * stC.x);
            const float p11 = __expf(s[1][1] + (aaC1.y == 0.0f ? NEGV : aaC1.y) + sbr[1] * stC.y);
            const float p12 = __expf(s[2][1] + (aaC1.z == 0.0f ? NEGV : aaC1.z) + sbr[1] * stC.z);
            const float p13 = __expf(s[3][1] + (aaC1.w == 0.0f ? NEGV : aaC1.w) + sbr[1] * stC.w);
            den[1] += (p10 + p11) + (p12 + p13);
            ushort4 pw; pw.x = f2bf(p10); pw.y = f2bf(p11); pw.z = f2bf(p12); pw.w = f2bf(p13);
            *(ushort4*)&ps[m0 + quad * 4 + 1][n16 * 4] = pw;
        }
        {
            const float p20 = __expf(s[0][2] + (aaC2.x == 0.0f ? NEGV : aaC2.x) + sbr[2] * stC.x);
            const float p21 = __expf(s[1][2] + (aaC2.y == 0.0f ? NEGV : aaC2.y) + sbr[2] * stC.y);
            const float p22 = __expf(s[2][2] + (aaC2.z == 0.0f ? NEGV : aaC2.z) + sbr[2] * stC.z);
            const float p23 = __expf(s[3][2] + (aaC2.w == 0.0f ? NEGV : aaC2.w) + sbr[2] * stC.w);
            den[2] += (p20 + p21) + (p22 + p23);
            ushort4 pw; pw.x = f2bf(p20); pw.y = f2bf(p21); pw.z = f2bf(p22); pw.w = f2bf(p23);
            *(ushort4*)&ps[m0 + quad * 4 + 2][n16 * 4] = pw;
        }
        {
            const float p30 = __expf(s[0][3] + (aaC3.x == 0.0f ? NEGV : aaC3.x) + sbr[3] * stC.x);
            const float p31 = __expf(s[1][3] + (aaC3.y == 0.0f ? NEGV : aaC3.y) + sbr[3] * stC.y);
            const float p32 = __expf(s[2][3] + (aaC3.z == 0.0f ? NEGV : aaC3.z) + sbr[3] * stC.z);
            const float p33 = __expf(s[3][3] + (aaC3.w == 0.0f ? NEGV : aaC3.w) + sbr[3] * stC.w);
            den[3] += (p30 + p31) + (p32 + p33);
            ushort4 pw; pw.x = f2bf(p30); pw.y = f2bf(p31); pw.z = f2bf(p32); pw.w = f2bf(p33);
            *(ushort4*)&ps[m0 + quad * 4 + 3][n16 * 4] = pw;
        }

        // PV: A-frags from wave-private ps (lgkm wait only, no barrier)
        const bf16x8 ap0 = *(const bf16x8*)&ps[m0 + n16][quad * 8];
        const bf16x8 ap1 = *(const bf16x8*)&ps[m0 + n16][32 + quad * 8];
        #pragma unroll
        for (int nt = 0; nt < 4; nt++) {
            const bf16x8 b0 = *(const bf16x8*)&mfb[(nt * 2 + 0) * 512 + fragoff];
            const bf16x8 b1 = *(const bf16x8*)&mfb[(nt * 2 + 1) * 512 + fragoff];
            acc[nt] = __builtin_amdgcn_mfma_f32_16x16x32_bf16(ap0, b0, acc[nt], 0, 0, 0);
            acc[nt] = __builtin_amdgcn_mfma_f32_16x16x32_bf16(ap1, b1, acc[nt], 0, 0, 0);
        }

        // rotate prefetch registers (renamed away by unroll-2)
        aaC0 = aaN0; aaC1 = aaN1; aaC2 = aaN2; aaC3 = aaN3; stC = stN;
    }

    // write agg partials (NT: write-once, read by final_k) + reduced denominators
    float* aggp = ws + WS_AGG + (size_t)sp * N * 64;
    #pragma unroll
    for (int nt = 0; nt < 4; nt++) {
        #pragma unroll
        for (int reg = 0; reg < 4; reg++) {
            __builtin_nontemporal_store(acc[nt][reg],
                &aggp[(size_t)(i0 + m0 + quad * 4 + reg) * 64 + nt * 16 + n16]);
        }
    }
    #pragma unroll
    for (int reg = 0; reg < 4; reg++) {
        float d = den[reg];
        d += __shfl_xor(d, 1, 64);
        d += __shfl_xor(d, 2, 64);
        d += __shfl_xor(d, 4, 64);
        d += __shfl_xor(d, 8, 64);
        if (n16 == 0) ws[WS_DEN + sp * N + i0 + m0 + quad * 4 + reg] = d;
    }
}

// ---------------- Kernel D: combine + LayerNorm + final MLP ----------------
__global__ __launch_bounds__(256) void final_k(
    const float* __restrict__ sa, const float* __restrict__ ln_g,
    const float* __restrict__ ln_b,
    const float* __restrict__ wa1, const float* __restrict__ ba1,
    const float* __restrict__ wa2, const float* __restrict__ ba2,
    const float* __restrict__ ws, float* __restrict__ out)
{
    const int w = threadIdx.x >> 6, lane = threadIdx.x & 63;
    const int row = blockIdx.x * 4 + w;
    __shared__ float es[4][64], hs2[4][64];
    float a = 0.0f;
    #pragma unroll
    for (int sp = 0; sp < NSPLIT; sp++)
        a += ws[WS_AGG + (size_t)sp * N * 64 + (size_t)row * 64 + lane];
    float d = 0.0f;
    #pragma unroll
    for (int sp = 0; sp < NSPLIT; sp++) d += ws[WS_DEN + sp * N + row];
    const float z = ws[WS_H + row * 64 + lane] + a / d;
    float mu = z;
    for (int off = 32; off; off >>= 1) mu += __shfl_xor(mu, off, 64);
    mu *= (1.0f / 64.0f);
    const float zc = z - mu;
    float var = zc * zc;
    for (int off = 32; off; off >>= 1) var += __shfl_xor(var, off, 64);
    var *= (1.0f / 64.0f);
    const float emb = zc * rsqrtf(var + EPSV) * ln_g[lane] + ln_b[lane];
    es[w][lane] = emb;
    __syncthreads();
    const float sa0 = sa[row * 2], sa1 = sa[row * 2 + 1];
    float hv = ba1[lane];
    #pragma unroll 8
    for (int c = 0; c < 64; c++) hv = fmaf(es[w][c], wa1[c * 64 + lane], hv);
    hv = fmaf(sa0, wa1[64 * 64 + lane], hv);
    hv = fmaf(sa1, wa1[65 * 64 + lane], hv);
    hs2[w][lane] = fmaxf(hv, 0.0f);
    __syncthreads();
    if (lane < 3) {
        float o = ba2[lane];
        for (int u = 0; u < 64; u++) o = fmaf(hs2[w][u], wa2[u * 3 + lane], o);
        out[row * 3 + lane] = o;
    }
}

extern "C" void kernel_launch(void* const* d_in, const int* in_sizes, int n_in,
                              void* d_out, int out_size, void* d_ws, size_t ws_size,
                              hipStream_t stream)
{
    const float* nf  = (const float*)d_in[0];
    const float* adj = (const float*)d_in[1];
    const float* tc  = (const float*)d_in[2];
    const float* sa  = (const float*)d_in[3];
    const float* w1  = (const float*)d_in[4];
    const float* b1  = (const float*)d_in[5];
    const float* w2  = (const float*)d_in[6];
    const float* b2  = (const float*)d_in[7];
    const float* wq  = (const float*)d_in[8];
    const float* bq  = (const float*)d_in[9];
    const float* wk  = (const float*)d_in[10];
    const float* bk  = (const float*)d_in[11];
    const float* wg  = (const float*)d_in[12];
    const float* bg  = (const float*)d_in[13];
    const float* sb  = (const float*)d_in[14];
    const float* wm  = (const float*)d_in[15];
    const float* bm  = (const float*)d_in[16];
    const float* lng = (const float*)d_in[17];
    const float* lnb = (const float*)d_in[18];
    const float* wa1 = (const float*)d_in[19];
    const float* ba1 = (const float*)d_in[20];
    const float* wa2 = (const float*)d_in[21];
    const float* ba2 = (const float*)d_in[22];
    float* ws  = (float*)d_ws;
    float* out = (float*)d_out;

    prep_k<<<1, 64, 0, stream>>>(tc, wg, bg, sb, ws + WS_SCAL);
    embed_k<<<N / 4, 256, 0, stream>>>(nf, tc, w1, b1, w2, b2, wq, bq, wk, bk,
                                       wm, bm, ws);
    mfrag_k<<<N / 64, 256, 0, stream>>>(ws);
    attn_k<<<dim3(N / 64, NSPLIT), 256, 0, stream>>>(adj, ws);
    final_k<<<N / 4, 256, 0, stream>>>(sa, lng, lnb, wa1, ba1, wa2, ba2, ws, out);
}